// Round 9
// baseline (536.411 us; speedup 1.0000x reference)
//
#include <hip/hip_runtime.h>
#include <hip/hip_cooperative_groups.h>

namespace cg = cooperative_groups;

#define NN 50000
#define NE 800000
#define C 128
#define SCAN_BLOCKS ((NN + 255) / 256)   // 196
#define PRE_BLOCKS (NE / (256 * 8))      // 391 blocks needed? NE/(2048)=390.625 -> use 391
#define ASTRIDE 136                       // bf16 elems per LDS A row (16B-aligned rows, bank shift)

typedef __attribute__((ext_vector_type(8))) short bf16x8;
typedef __attribute__((ext_vector_type(4))) float f32x4;
typedef unsigned short ushort;

__device__ inline ushort bf16_rn(float f) {
    unsigned u = __builtin_bit_cast(unsigned, f);
    u += 0x7FFF + ((u >> 16) & 1);
    return (ushort)(u >> 16);
}
__device__ inline void split_bf16(float f, ushort& hi, ushort& lo) {
    hi = bf16_rn(f);
    float hif = __builtin_bit_cast(float, (unsigned)hi << 16);
    lo = bf16_rn(f - hif);               // residual, ~2^-17 rel total
}
__device__ inline float bf_lo(unsigned u) { return __builtin_bit_cast(float, u << 16); }
__device__ inline float bf_hi(unsigned u) { return __builtin_bit_cast(float, u & 0xFFFF0000u); }

// ---------------- one cooperative kernel: zero + count_pos/split + scan + fill ----------

__global__ __launch_bounds__(256)
void preproc_kernel(const int* __restrict__ src, const int* __restrict__ dst,
                    const float* __restrict__ x,
                    int* __restrict__ deg, int* __restrict__ row_ptr,
                    int* __restrict__ pos, int* __restrict__ col,
                    int* __restrict__ bsum, int* __restrict__ boff,
                    ushort* __restrict__ Ah, ushort* __restrict__ Al) {
    cg::grid_group grid = cg::this_grid();
    __shared__ int wsum[4];
    __shared__ int wpre[4];
    int t = threadIdx.x, lane = t & 63, w = t >> 6;
    int gid = blockIdx.x * 256 + t;
    int nthreads = gridDim.x * 256;

    // ---- phase 0: zero deg ----
    for (int i = gid; i < NN; i += nthreads) deg[i] = 0;
    grid.sync();

    // ---- phase A: count_pos (edge blocks) + split x -> hi/lo (grid-stride) ----
    {
        int e0 = gid * 8;
        if (e0 < NE) {
            int4 a = *(const int4*)(dst + e0);
            int4 b = *(const int4*)(dst + e0 + 4);
            int p0 = atomicAdd(&deg[a.x], 1);
            int p1 = atomicAdd(&deg[a.y], 1);
            int p2 = atomicAdd(&deg[a.z], 1);
            int p3 = atomicAdd(&deg[a.w], 1);
            int p4 = atomicAdd(&deg[b.x], 1);
            int p5 = atomicAdd(&deg[b.y], 1);
            int p6 = atomicAdd(&deg[b.z], 1);
            int p7 = atomicAdd(&deg[b.w], 1);
            *(int4*)(pos + e0)     = make_int4(p0, p1, p2, p3);
            *(int4*)(pos + e0 + 4) = make_int4(p4, p5, p6, p7);
        }
        for (int i = gid; i < NN * C / 4; i += nthreads) {
            f32x4 v = ((const f32x4*)x)[i];
            ushort h0, h1, h2, h3, l0, l1, l2, l3;
            split_bf16(v.x, h0, l0);
            split_bf16(v.y, h1, l1);
            split_bf16(v.z, h2, l2);
            split_bf16(v.w, h3, l3);
            *(uint2*)(Ah + (size_t)i * 4) = make_uint2((unsigned)h0 | ((unsigned)h1 << 16),
                                                       (unsigned)h2 | ((unsigned)h3 << 16));
            *(uint2*)(Al + (size_t)i * 4) = make_uint2((unsigned)l0 | ((unsigned)l1 << 16),
                                                       (unsigned)l2 | ((unsigned)l3 << 16));
        }
    }
    grid.sync();

    // ---- phase B: scan1 — block-local exclusive scan of deg (first 196 blocks) ----
    if (blockIdx.x < SCAN_BLOCKS) {
        int i = blockIdx.x * 256 + t;
        int v = (i < NN) ? deg[i] : 0;
        int s = v;
        #pragma unroll
        for (int off = 1; off < 64; off <<= 1) {
            int y = __shfl_up(s, off, 64);
            if (lane >= off) s += y;
        }
        if (lane == 63) wsum[w] = s;
        __syncthreads();
        if (t == 0) {
            int acc = 0;
            #pragma unroll
            for (int j = 0; j < 4; ++j) { wpre[j] = acc; acc += wsum[j]; }
            bsum[blockIdx.x] = acc;
        }
        __syncthreads();
        if (i < NN) row_ptr[i] = wpre[w] + (s - v);
    }
    grid.sync();

    // ---- phase C: scan2 — block 0 scans the 196 block sums ----
    if (blockIdx.x == 0) {
        int v = (t < SCAN_BLOCKS) ? bsum[t] : 0;
        int s = v;
        #pragma unroll
        for (int off = 1; off < 64; off <<= 1) {
            int y = __shfl_up(s, off, 64);
            if (lane >= off) s += y;
        }
        if (lane == 63) wsum[w] = s;
        __syncthreads();
        if (t == 0) {
            int acc = 0;
            #pragma unroll
            for (int j = 0; j < 4; ++j) { wpre[j] = acc; acc += wsum[j]; }
            row_ptr[NN] = acc;
        }
        __syncthreads();
        if (t < SCAN_BLOCKS) boff[t] = wpre[w] + (s - v);
    }
    grid.sync();

    // ---- phase D: scan3 — add block offsets ----
    if (blockIdx.x < SCAN_BLOCKS) {
        int i = blockIdx.x * 256 + t;
        if (i < NN) row_ptr[i] += boff[blockIdx.x];
    }
    grid.sync();

    // ---- phase E: fill — atomic-free placement ----
    {
        int e0 = gid * 8;
        if (e0 < NE) {
            int4 da = *(const int4*)(dst + e0);
            int4 db = *(const int4*)(dst + e0 + 4);
            int4 sa = *(const int4*)(src + e0);
            int4 sb = *(const int4*)(src + e0 + 4);
            int4 pa = *(const int4*)(pos + e0);
            int4 pb = *(const int4*)(pos + e0 + 4);
            col[row_ptr[da.x] + pa.x] = sa.x;
            col[row_ptr[da.y] + pa.y] = sa.y;
            col[row_ptr[da.z] + pa.z] = sa.z;
            col[row_ptr[da.w] + pa.w] = sa.w;
            col[row_ptr[db.x] + pb.x] = sb.x;
            col[row_ptr[db.y] + pb.y] = sb.y;
            col[row_ptr[db.z] + pb.z] = sb.z;
            col[row_ptr[db.w] + pb.w] = sb.w;
        }
    }
}

// ---------------- mean aggregation: one wave per node, 4 edge-rows per VMEM instr ----
// Row = 256 B of bf16-hi. 16 lanes x uint4 (16 B) per edge-row; quad = lane>>4 picks
// which of 4 consecutive edges; 2 loads in flight = 8 edge-rows. Cross-quad shfl reduce.

__global__ __launch_bounds__(256)
void agg_kernel(const ushort* __restrict__ xh, const int* __restrict__ row_ptr,
                const int* __restrict__ col, float* __restrict__ agg, int nodes) {
    int node = (blockIdx.x * blockDim.x + threadIdx.x) >> 6;
    int lane = threadIdx.x & 63;
    if (node >= nodes) return;
    int quad = lane >> 4;        // which edge within a group of 4
    int ql   = lane & 15;        // channel group: ch [ql*8, ql*8+8)
    int start = row_ptr[node], end = row_ptr[node + 1];
    const uint4* xr = (const uint4*)xh;   // row = 16 uint4
    float a0=0,a1=0,a2=0,a3=0,a4=0,a5=0,a6=0,a7=0;
    int e = start;
    for (; e + 7 < end; e += 8) {
        int i0 = col[e + quad];
        int i1 = col[e + 4 + quad];
        uint4 u0 = xr[(size_t)i0 * 16 + ql];
        uint4 u1 = xr[(size_t)i1 * 16 + ql];
        a0 += bf_lo(u0.x) + bf_lo(u1.x); a1 += bf_hi(u0.x) + bf_hi(u1.x);
        a2 += bf_lo(u0.y) + bf_lo(u1.y); a3 += bf_hi(u0.y) + bf_hi(u1.y);
        a4 += bf_lo(u0.z) + bf_lo(u1.z); a5 += bf_hi(u0.z) + bf_hi(u1.z);
        a6 += bf_lo(u0.w) + bf_lo(u1.w); a7 += bf_hi(u0.w) + bf_hi(u1.w);
    }
    for (; e + 3 < end; e += 4) {
        uint4 u = xr[(size_t)col[e + quad] * 16 + ql];
        a0 += bf_lo(u.x); a1 += bf_hi(u.x);
        a2 += bf_lo(u.y); a3 += bf_hi(u.y);
        a4 += bf_lo(u.z); a5 += bf_hi(u.z);
        a6 += bf_lo(u.w); a7 += bf_hi(u.w);
    }
    int rem = end - e;           // 0..3
    if (quad < rem) {
        uint4 u = xr[(size_t)col[e + quad] * 16 + ql];
        a0 += bf_lo(u.x); a1 += bf_hi(u.x);
        a2 += bf_lo(u.y); a3 += bf_hi(u.y);
        a4 += bf_lo(u.z); a5 += bf_hi(u.z);
        a6 += bf_lo(u.w); a7 += bf_hi(u.w);
    }
    // reduce across the 4 quads (lanes ql, ql+16, ql+32, ql+48)
    a0 += __shfl_xor(a0, 16, 64); a0 += __shfl_xor(a0, 32, 64);
    a1 += __shfl_xor(a1, 16, 64); a1 += __shfl_xor(a1, 32, 64);
    a2 += __shfl_xor(a2, 16, 64); a2 += __shfl_xor(a2, 32, 64);
    a3 += __shfl_xor(a3, 16, 64); a3 += __shfl_xor(a3, 32, 64);
    a4 += __shfl_xor(a4, 16, 64); a4 += __shfl_xor(a4, 32, 64);
    a5 += __shfl_xor(a5, 16, 64); a5 += __shfl_xor(a5, 32, 64);
    a6 += __shfl_xor(a6, 16, 64); a6 += __shfl_xor(a6, 32, 64);
    a7 += __shfl_xor(a7, 16, 64); a7 += __shfl_xor(a7, 32, 64);
    if (quad == 0) {
        float inv = 1.0f / (float)max(end - start, 1);
        float* dst = agg + (size_t)node * C + ql * 8;
        *(f32x4*)dst       = (f32x4){a0 * inv, a1 * inv, a2 * inv, a3 * inv};
        *(f32x4*)(dst + 4) = (f32x4){a4 * inv, a5 * inv, a6 * inv, a7 * inv};
    }
}

// ---------------- fused dual GEMM + bias + PReLU via split-bf16 MFMA ----------------
// out = prelu( Ain@Wl.T + bl + X@Wr.T ); Ain fp32 (split in-kernel), X pre-split hi/lo.
// block = 256 (4 waves), tile 64 rows x 128 cols; wave = 32-col strip; W frags in regs.

__global__ __launch_bounds__(256, 3)
void gemm_kernel(const float* __restrict__ Ain,
                 const ushort* __restrict__ Xh, const ushort* __restrict__ Xl,
                 const float* __restrict__ Wl, const float* __restrict__ bl,
                 const float* __restrict__ Wr, const float* __restrict__ slope,
                 float* __restrict__ outf, ushort* __restrict__ outh,
                 ushort* __restrict__ outl, int rows) {
    __shared__ ushort Ahi[64 * ASTRIDE];
    __shared__ ushort Alo[64 * ASTRIDE];
    int t = threadIdx.x;
    int lane = t & 63;
    int w = t >> 6;
    int l = lane & 15;
    int q = lane >> 4;
    int row0 = blockIdx.x * 64;

    f32x4 acc[4][2];
    #pragma unroll
    for (int mt = 0; mt < 4; ++mt)
        #pragma unroll
        for (int nt = 0; nt < 2; ++nt)
            acc[mt][nt] = (f32x4){0.f, 0.f, 0.f, 0.f};

    #pragma unroll
    for (int mat = 0; mat < 2; ++mat) {
        const float* W = mat ? Wr : Wl;

        // W fragments (hi/lo) into registers: B[k][n], n = lane&15, k = q*8+j
        bf16x8 bhi[2][4], blo[2][4];
        #pragma unroll
        for (int nt = 0; nt < 2; ++nt) {
            int n = w * 32 + nt * 16 + l;
            const float* wp = W + n * C + q * 8;
            #pragma unroll
            for (int kb = 0; kb < 4; ++kb) {
                f32x4 w0 = *(const f32x4*)(wp + kb * 32);
                f32x4 w1 = *(const f32x4*)(wp + kb * 32 + 4);
                float f[8] = {w0.x, w0.y, w0.z, w0.w, w1.x, w1.y, w1.z, w1.w};
                bf16x8 h, o;
                #pragma unroll
                for (int j = 0; j < 8; ++j) {
                    ushort hh, ll;
                    split_bf16(f[j], hh, ll);
                    h[j] = (short)hh;
                    o[j] = (short)ll;
                }
                bhi[nt][kb] = h;
                blo[nt][kb] = o;
            }
        }

        __syncthreads();                 // protect previous mat's frag reads
        int ar = t >> 2;                 // row 0..63
        int aq = t & 3;                  // k quarter: 32 ushorts
        int r = min(row0 + ar, rows - 1);
        ushort* dh = Ahi + ar * ASTRIDE + aq * 32;
        ushort* dl = Alo + ar * ASTRIDE + aq * 32;
        if (mat == 0) {
            const float* ap = Ain + (size_t)r * C + aq * 32;
            #pragma unroll
            for (int i = 0; i < 8; ++i) {
                f32x4 v = *(const f32x4*)(ap + i * 4);
                ushort h0, h1, h2, h3, l0, l1, l2, l3;
                split_bf16(v.x, h0, l0);
                split_bf16(v.y, h1, l1);
                split_bf16(v.z, h2, l2);
                split_bf16(v.w, h3, l3);
                *(uint2*)(dh + i * 4) = make_uint2((unsigned)h0 | ((unsigned)h1 << 16),
                                                   (unsigned)h2 | ((unsigned)h3 << 16));
                *(uint2*)(dl + i * 4) = make_uint2((unsigned)l0 | ((unsigned)l1 << 16),
                                                   (unsigned)l2 | ((unsigned)l3 << 16));
            }
        } else {
            const ushort* ph = Xh + (size_t)r * C + aq * 32;
            const ushort* pl = Xl + (size_t)r * C + aq * 32;
            #pragma unroll
            for (int i = 0; i < 4; ++i) {        // 4 x uint4 = 32 ushorts
                *(uint4*)(dh + i * 8) = *(const uint4*)(ph + i * 8);
                *(uint4*)(dl + i * 8) = *(const uint4*)(pl + i * 8);
            }
        }
        __syncthreads();

        // K loop: 4 k-blocks x 4 m-tiles x 2 n-tiles x 3 products
        #pragma unroll
        for (int kb = 0; kb < 4; ++kb) {
            #pragma unroll
            for (int mt = 0; mt < 4; ++mt) {
                int off = (mt * 16 + l) * ASTRIDE + kb * 32 + q * 8;
                bf16x8 ahi = *(const bf16x8*)(Ahi + off);
                bf16x8 alo = *(const bf16x8*)(Alo + off);
                #pragma unroll
                for (int nt = 0; nt < 2; ++nt) {
                    acc[mt][nt] = __builtin_amdgcn_mfma_f32_16x16x32_bf16(ahi, bhi[nt][kb], acc[mt][nt], 0, 0, 0);
                    acc[mt][nt] = __builtin_amdgcn_mfma_f32_16x16x32_bf16(alo, bhi[nt][kb], acc[mt][nt], 0, 0, 0);
                    acc[mt][nt] = __builtin_amdgcn_mfma_f32_16x16x32_bf16(ahi, blo[nt][kb], acc[mt][nt], 0, 0, 0);
                }
            }
        }
    }

    // epilogue: bias + PReLU; write fp32 (final layer) or hi/lo (hidden layers)
    #pragma unroll
    for (int nt = 0; nt < 2; ++nt) {
        int n = w * 32 + nt * 16 + l;
        float b = bl[n], s = slope[n];
        #pragma unroll
        for (int mt = 0; mt < 4; ++mt) {
            #pragma unroll
            for (int rg = 0; rg < 4; ++rg) {
                int r = row0 + mt * 16 + q * 4 + rg;
                if (r < rows) {
                    float v = acc[mt][nt][rg] + b;
                    v = v > 0.f ? v : s * v;
                    if (outf) {
                        outf[(size_t)r * C + n] = v;
                    } else {
                        ushort hh, ll;
                        split_bf16(v, hh, ll);
                        outh[(size_t)r * C + n] = hh;
                        outl[(size_t)r * C + n] = ll;
                    }
                }
            }
        }
    }
}

// ---------------- launch ----------------

extern "C" void kernel_launch(void* const* d_in, const int* in_sizes, int n_in,
                              void* d_out, int out_size, void* d_ws, size_t ws_size,
                              hipStream_t stream) {
    const float* x   = (const float*)d_in[0];
    const int*   src = (const int*)d_in[1];
    const int*   dst = src + NE;
    const float* Wl[3] = {(const float*)d_in[3], (const float*)d_in[7],  (const float*)d_in[11]};
    const float* bl[3] = {(const float*)d_in[4], (const float*)d_in[8],  (const float*)d_in[12]};
    const float* Wr[3] = {(const float*)d_in[5], (const float*)d_in[9],  (const float*)d_in[13]};
    const float* sl[3] = {(const float*)d_in[6], (const float*)d_in[10], (const float*)d_in[14]};

    int*   deg     = (int*)d_ws;             // 50016
    int*   row_ptr = deg + 50016;            // 50016 (uses 50001)
    int*   col     = row_ptr + 50016;        // 800000
    int*   pos     = col + 800000;           // 800000
    int*   bsum    = pos + 800000;           // 256
    int*   boff    = bsum + 256;             // 256
    float* agg     = (float*)(boff + 256);   // NN*C fp32 (16B-aligned)
    ushort* Ah     = (ushort*)(agg + (size_t)NN * C);   // ping hi
    ushort* Al     = Ah + (size_t)NN * C;    // ping lo
    ushort* Bh     = Al + (size_t)NN * C;    // pong hi
    ushort* Bl     = Bh + (size_t)NN * C;    // pong lo

    // one cooperative dispatch: zero + count/split + scan + fill
    {
        void* args[] = {(void*)&src, (void*)&dst, (void*)&x,
                        (void*)&deg, (void*)&row_ptr, (void*)&pos, (void*)&col,
                        (void*)&bsum, (void*)&boff, (void*)&Ah, (void*)&Al};
        hipLaunchCooperativeKernel((const void*)preproc_kernel,
                                   dim3((NE / 8 + 255) / 256), dim3(256),
                                   args, 0, stream);
    }

    int rows_out = out_size / C;             // 1024

    // layer 0: A -> B
    agg_kernel<<<(NN + 3) / 4, 256, 0, stream>>>(Ah, row_ptr, col, agg, NN);
    gemm_kernel<<<(NN + 63) / 64, 256, 0, stream>>>(agg, Ah, Al, Wl[0], bl[0], Wr[0], sl[0],
                                                    nullptr, Bh, Bl, NN);

    // layer 1: B -> A
    agg_kernel<<<(NN + 3) / 4, 256, 0, stream>>>(Bh, row_ptr, col, agg, NN);
    gemm_kernel<<<(NN + 63) / 64, 256, 0, stream>>>(agg, Bh, Bl, Wl[1], bl[1], Wr[1], sl[1],
                                                    nullptr, Ah, Al, NN);

    // layer 2: A -> d_out (first rows_out nodes only)
    agg_kernel<<<(rows_out + 3) / 4, 256, 0, stream>>>(Ah, row_ptr, col, agg, rows_out);
    gemm_kernel<<<(rows_out + 63) / 64, 256, 0, stream>>>(agg, Ah, Al, Wl[2], bl[2], Wr[2], sl[2],
                                                          (float*)d_out, nullptr, nullptr, rows_out);
}

// Round 10
// 312.208 us; speedup vs baseline: 1.7181x; 1.7181x over previous
//
#include <hip/hip_runtime.h>

#define NN 50000
#define NE 800000
#define C 128
#define SCAN_BLOCKS ((NN + 255) / 256)   // 196
#define E8B ((NE / 8 + 255) / 256)       // 391 edge blocks (8 edges/thread)
#define SPLITB 1563                      // split blocks: 1563*256 = 400128 threads
#define ASTRIDE 136                      // bf16 elems per LDS A row (16B-aligned rows, bank shift)

typedef __attribute__((ext_vector_type(8))) short bf16x8;
typedef __attribute__((ext_vector_type(4))) float f32x4;
typedef unsigned short ushort;

__device__ inline ushort bf16_rn(float f) {
    unsigned u = __builtin_bit_cast(unsigned, f);
    u += 0x7FFF + ((u >> 16) & 1);
    return (ushort)(u >> 16);
}
__device__ inline void split_bf16(float f, ushort& hi, ushort& lo) {
    hi = bf16_rn(f);
    float hif = __builtin_bit_cast(float, (unsigned)hi << 16);
    lo = bf16_rn(f - hif);               // residual, ~2^-17 rel total
}
__device__ inline float bf_lo(unsigned u) { return __builtin_bit_cast(float, u << 16); }
__device__ inline float bf_hi(unsigned u) { return __builtin_bit_cast(float, u & 0xFFFF0000u); }

// ---------------- pass 1 (fused): count_pos (edge blocks) + split x (elem blocks) ----
// Blocks [0, E8B): degree count + per-edge slot, 8 independent atomic chains/thread.
// Blocks [E8B, E8B+SPLITB): fp32 x -> bf16 hi/lo shadow arrays, grid-stride.

__global__ __launch_bounds__(256)
void count_split_kernel(const int* __restrict__ dst, const float* __restrict__ x,
                        int* __restrict__ deg, int* __restrict__ pos,
                        ushort* __restrict__ Ah, ushort* __restrict__ Al) {
    int t = threadIdx.x;
    if (blockIdx.x < E8B) {
        int e0 = (blockIdx.x * 256 + t) * 8;
        if (e0 >= NE) return;
        int4 a = *(const int4*)(dst + e0);
        int4 b = *(const int4*)(dst + e0 + 4);
        int p0 = atomicAdd(&deg[a.x], 1);
        int p1 = atomicAdd(&deg[a.y], 1);
        int p2 = atomicAdd(&deg[a.z], 1);
        int p3 = atomicAdd(&deg[a.w], 1);
        int p4 = atomicAdd(&deg[b.x], 1);
        int p5 = atomicAdd(&deg[b.y], 1);
        int p6 = atomicAdd(&deg[b.z], 1);
        int p7 = atomicAdd(&deg[b.w], 1);
        *(int4*)(pos + e0)     = make_int4(p0, p1, p2, p3);
        *(int4*)(pos + e0 + 4) = make_int4(p4, p5, p6, p7);
    } else {
        int tid = (blockIdx.x - E8B) * 256 + t;
        const int total = NN * C / 4;            // 1.6M f32x4 elements
        for (int i = tid; i < total; i += SPLITB * 256) {
            f32x4 v = ((const f32x4*)x)[i];
            ushort h0, h1, h2, h3, l0, l1, l2, l3;
            split_bf16(v.x, h0, l0);
            split_bf16(v.y, h1, l1);
            split_bf16(v.z, h2, l2);
            split_bf16(v.w, h3, l3);
            *(uint2*)(Ah + (size_t)i * 4) = make_uint2((unsigned)h0 | ((unsigned)h1 << 16),
                                                       (unsigned)h2 | ((unsigned)h3 << 16));
            *(uint2*)(Al + (size_t)i * 4) = make_uint2((unsigned)l0 | ((unsigned)l1 << 16),
                                                       (unsigned)l2 | ((unsigned)l3 << 16));
        }
    }
}

// ---------------- scan1: block-local exclusive scan of deg (row_ptr stays block-local) --
// writes indices [blk*256, blk*256+256), including index NN (deg treated 0 past NN).

__global__ __launch_bounds__(256)
void scan1_kernel(const int* __restrict__ deg, int* __restrict__ row_ptr,
                  int* __restrict__ bsum) {
    __shared__ int wsum[4];
    __shared__ int wpre[4];
    int t = threadIdx.x, lane = t & 63, w = t >> 6;
    int i = blockIdx.x * 256 + t;
    int v = (i < NN) ? deg[i] : 0;
    int s = v;
    #pragma unroll
    for (int off = 1; off < 64; off <<= 1) {
        int y = __shfl_up(s, off, 64);
        if (lane >= off) s += y;
    }
    if (lane == 63) wsum[w] = s;
    __syncthreads();
    if (t == 0) {
        int acc = 0;
        #pragma unroll
        for (int j = 0; j < 4; ++j) { wpre[j] = acc; acc += wsum[j]; }
        bsum[blockIdx.x] = acc;
    }
    __syncthreads();
    if (i <= NN) row_ptr[i] = wpre[w] + (s - v);   // block-local exclusive
}

// ---------------- scan2: block offsets (exclusive scan of the 196 block sums) ---------

__global__ __launch_bounds__(256)
void scan2_kernel(const int* __restrict__ bsum, int* __restrict__ boff) {
    __shared__ int wsum[4];
    __shared__ int wpre[4];
    int t = threadIdx.x, lane = t & 63, w = t >> 6;
    int v = (t < SCAN_BLOCKS) ? bsum[t] : 0;
    int s = v;
    #pragma unroll
    for (int off = 1; off < 64; off <<= 1) {
        int y = __shfl_up(s, off, 64);
        if (lane >= off) s += y;
    }
    if (lane == 63) wsum[w] = s;
    __syncthreads();
    if (t == 0) {
        int acc = 0;
        #pragma unroll
        for (int j = 0; j < 4; ++j) { wpre[j] = acc; acc += wsum[j]; }
    }
    __syncthreads();
    if (t < SCAN_BLOCKS) boff[t] = wpre[w] + (s - v);
}

// ---------------- pass 2: placement, atomic-free; global base = rp[d] + boff[d>>8] ----

__global__ __launch_bounds__(256)
void fill2_kernel(const int* __restrict__ src, const int* __restrict__ dst,
                  const int* __restrict__ row_ptr, const int* __restrict__ boff,
                  const int* __restrict__ pos, int* __restrict__ col) {
    int e0 = (blockIdx.x * 256 + threadIdx.x) * 8;
    if (e0 >= NE) return;
    int4 da = *(const int4*)(dst + e0);
    int4 db = *(const int4*)(dst + e0 + 4);
    int4 sa = *(const int4*)(src + e0);
    int4 sb = *(const int4*)(src + e0 + 4);
    int4 pa = *(const int4*)(pos + e0);
    int4 pb = *(const int4*)(pos + e0 + 4);
    col[row_ptr[da.x] + boff[da.x >> 8] + pa.x] = sa.x;
    col[row_ptr[da.y] + boff[da.y >> 8] + pa.y] = sa.y;
    col[row_ptr[da.z] + boff[da.z >> 8] + pa.z] = sa.z;
    col[row_ptr[da.w] + boff[da.w >> 8] + pa.w] = sa.w;
    col[row_ptr[db.x] + boff[db.x >> 8] + pb.x] = sb.x;
    col[row_ptr[db.y] + boff[db.y >> 8] + pb.y] = sb.y;
    col[row_ptr[db.z] + boff[db.z >> 8] + pb.z] = sb.z;
    col[row_ptr[db.w] + boff[db.w >> 8] + pb.w] = sb.w;
}

// ---------------- mean aggregation: one wave per node, 4 edge-rows per VMEM instr ----
// Row = 256 B of bf16-hi. 16 lanes x uint4 per edge-row; quad picks 1 of 4 edges.
// Epilogue: mean -> split hi/lo -> 16B stores (feeds gemm A-operand directly).

__global__ __launch_bounds__(256)
void agg_kernel(const ushort* __restrict__ xh, const int* __restrict__ row_ptr,
                const int* __restrict__ boff, const int* __restrict__ col,
                ushort* __restrict__ aggh, ushort* __restrict__ aggl, int nodes) {
    int node = (blockIdx.x * blockDim.x + threadIdx.x) >> 6;
    int lane = threadIdx.x & 63;
    if (node >= nodes) return;
    int quad = lane >> 4;        // which edge within a group of 4
    int ql   = lane & 15;        // channel group: ch [ql*8, ql*8+8)
    int start = row_ptr[node] + boff[node >> 8];
    int end   = row_ptr[node + 1] + boff[(node + 1) >> 8];
    const uint4* xr = (const uint4*)xh;   // row = 16 uint4
    float a0=0,a1=0,a2=0,a3=0,a4=0,a5=0,a6=0,a7=0;
    int e = start;
    for (; e + 7 < end; e += 8) {
        int i0 = col[e + quad];
        int i1 = col[e + 4 + quad];
        uint4 u0 = xr[(size_t)i0 * 16 + ql];
        uint4 u1 = xr[(size_t)i1 * 16 + ql];
        a0 += bf_lo(u0.x) + bf_lo(u1.x); a1 += bf_hi(u0.x) + bf_hi(u1.x);
        a2 += bf_lo(u0.y) + bf_lo(u1.y); a3 += bf_hi(u0.y) + bf_hi(u1.y);
        a4 += bf_lo(u0.z) + bf_lo(u1.z); a5 += bf_hi(u0.z) + bf_hi(u1.z);
        a6 += bf_lo(u0.w) + bf_lo(u1.w); a7 += bf_hi(u0.w) + bf_hi(u1.w);
    }
    for (; e + 3 < end; e += 4) {
        uint4 u = xr[(size_t)col[e + quad] * 16 + ql];
        a0 += bf_lo(u.x); a1 += bf_hi(u.x);
        a2 += bf_lo(u.y); a3 += bf_hi(u.y);
        a4 += bf_lo(u.z); a5 += bf_hi(u.z);
        a6 += bf_lo(u.w); a7 += bf_hi(u.w);
    }
    int rem = end - e;           // 0..3
    if (quad < rem) {
        uint4 u = xr[(size_t)col[e + quad] * 16 + ql];
        a0 += bf_lo(u.x); a1 += bf_hi(u.x);
        a2 += bf_lo(u.y); a3 += bf_hi(u.y);
        a4 += bf_lo(u.z); a5 += bf_hi(u.z);
        a6 += bf_lo(u.w); a7 += bf_hi(u.w);
    }
    // reduce across the 4 quads (lanes ql, ql+16, ql+32, ql+48)
    a0 += __shfl_xor(a0, 16, 64); a0 += __shfl_xor(a0, 32, 64);
    a1 += __shfl_xor(a1, 16, 64); a1 += __shfl_xor(a1, 32, 64);
    a2 += __shfl_xor(a2, 16, 64); a2 += __shfl_xor(a2, 32, 64);
    a3 += __shfl_xor(a3, 16, 64); a3 += __shfl_xor(a3, 32, 64);
    a4 += __shfl_xor(a4, 16, 64); a4 += __shfl_xor(a4, 32, 64);
    a5 += __shfl_xor(a5, 16, 64); a5 += __shfl_xor(a5, 32, 64);
    a6 += __shfl_xor(a6, 16, 64); a6 += __shfl_xor(a6, 32, 64);
    a7 += __shfl_xor(a7, 16, 64); a7 += __shfl_xor(a7, 32, 64);
    if (quad == 0) {
        float inv = 1.0f / (float)max(end - start, 1);
        float m[8] = {a0*inv, a1*inv, a2*inv, a3*inv, a4*inv, a5*inv, a6*inv, a7*inv};
        ushort h[8], o[8];
        #pragma unroll
        for (int j = 0; j < 8; ++j) split_bf16(m[j], h[j], o[j]);
        size_t off = (size_t)node * C + ql * 8;
        *(uint4*)(aggh + off) = make_uint4((unsigned)h[0] | ((unsigned)h[1] << 16),
                                           (unsigned)h[2] | ((unsigned)h[3] << 16),
                                           (unsigned)h[4] | ((unsigned)h[5] << 16),
                                           (unsigned)h[6] | ((unsigned)h[7] << 16));
        *(uint4*)(aggl + off) = make_uint4((unsigned)o[0] | ((unsigned)o[1] << 16),
                                           (unsigned)o[2] | ((unsigned)o[3] << 16),
                                           (unsigned)o[4] | ((unsigned)o[5] << 16),
                                           (unsigned)o[6] | ((unsigned)o[7] << 16));
    }
}

// ---------------- fused dual GEMM + bias + PReLU via split-bf16 MFMA ----------------
// out = prelu( A@Wl.T + bl + X@Wr.T ); both operands pre-split hi/lo (identical staging).
// block = 256 (4 waves), tile 64 rows x 128 cols; wave = 32-col strip; W frags in regs.

__global__ __launch_bounds__(256, 3)
void gemm_kernel(const ushort* __restrict__ Ah, const ushort* __restrict__ Al,
                 const ushort* __restrict__ Xh, const ushort* __restrict__ Xl,
                 const float* __restrict__ Wl, const float* __restrict__ bl,
                 const float* __restrict__ Wr, const float* __restrict__ slope,
                 float* __restrict__ outf, ushort* __restrict__ outh,
                 ushort* __restrict__ outl, int rows) {
    __shared__ ushort Ahi[64 * ASTRIDE];
    __shared__ ushort Alo[64 * ASTRIDE];
    int t = threadIdx.x;
    int lane = t & 63;
    int w = t >> 6;
    int l = lane & 15;
    int q = lane >> 4;
    int row0 = blockIdx.x * 64;

    f32x4 acc[4][2];
    #pragma unroll
    for (int mt = 0; mt < 4; ++mt)
        #pragma unroll
        for (int nt = 0; nt < 2; ++nt)
            acc[mt][nt] = (f32x4){0.f, 0.f, 0.f, 0.f};

    #pragma unroll
    for (int mat = 0; mat < 2; ++mat) {
        const float* W = mat ? Wr : Wl;
        const ushort* Ph = mat ? Xh : Ah;
        const ushort* Pl = mat ? Xl : Al;

        // W fragments (hi/lo) into registers: B[k][n], n = lane&15, k = q*8+j
        bf16x8 bhi[2][4], blo[2][4];
        #pragma unroll
        for (int nt = 0; nt < 2; ++nt) {
            int n = w * 32 + nt * 16 + l;
            const float* wp = W + n * C + q * 8;
            #pragma unroll
            for (int kb = 0; kb < 4; ++kb) {
                f32x4 w0 = *(const f32x4*)(wp + kb * 32);
                f32x4 w1 = *(const f32x4*)(wp + kb * 32 + 4);
                float f[8] = {w0.x, w0.y, w0.z, w0.w, w1.x, w1.y, w1.z, w1.w};
                bf16x8 h, o;
                #pragma unroll
                for (int j = 0; j < 8; ++j) {
                    ushort hh, ll;
                    split_bf16(f[j], hh, ll);
                    h[j] = (short)hh;
                    o[j] = (short)ll;
                }
                bhi[nt][kb] = h;
                blo[nt][kb] = o;
            }
        }

        __syncthreads();                 // protect previous mat's frag reads
        int ar = t >> 2;                 // row 0..63
        int aq = t & 3;                  // k quarter: 32 ushorts
        int r = min(row0 + ar, rows - 1);
        ushort* dh = Ahi + ar * ASTRIDE + aq * 32;
        ushort* dl = Alo + ar * ASTRIDE + aq * 32;
        const ushort* ph = Ph + (size_t)r * C + aq * 32;
        const ushort* pl = Pl + (size_t)r * C + aq * 32;
        #pragma unroll
        for (int i = 0; i < 4; ++i) {    // 4 x uint4 = 32 ushorts
            *(uint4*)(dh + i * 8) = *(const uint4*)(ph + i * 8);
            *(uint4*)(dl + i * 8) = *(const uint4*)(pl + i * 8);
        }
        __syncthreads();

        // K loop: 4 k-blocks x 4 m-tiles x 2 n-tiles x 3 products
        #pragma unroll
        for (int kb = 0; kb < 4; ++kb) {
            #pragma unroll
            for (int mt = 0; mt < 4; ++mt) {
                int off = (mt * 16 + l) * ASTRIDE + kb * 32 + q * 8;
                bf16x8 ahi = *(const bf16x8*)(Ahi + off);
                bf16x8 alo = *(const bf16x8*)(Alo + off);
                #pragma unroll
                for (int nt = 0; nt < 2; ++nt) {
                    acc[mt][nt] = __builtin_amdgcn_mfma_f32_16x16x32_bf16(ahi, bhi[nt][kb], acc[mt][nt], 0, 0, 0);
                    acc[mt][nt] = __builtin_amdgcn_mfma_f32_16x16x32_bf16(alo, bhi[nt][kb], acc[mt][nt], 0, 0, 0);
                    acc[mt][nt] = __builtin_amdgcn_mfma_f32_16x16x32_bf16(ahi, blo[nt][kb], acc[mt][nt], 0, 0, 0);
                }
            }
        }
    }

    // epilogue: bias + PReLU; write fp32 (final layer) or hi/lo (hidden layers)
    #pragma unroll
    for (int nt = 0; nt < 2; ++nt) {
        int n = w * 32 + nt * 16 + l;
        float b = bl[n], s = slope[n];
        #pragma unroll
        for (int mt = 0; mt < 4; ++mt) {
            #pragma unroll
            for (int rg = 0; rg < 4; ++rg) {
                int r = row0 + mt * 16 + q * 4 + rg;
                if (r < rows) {
                    float v = acc[mt][nt][rg] + b;
                    v = v > 0.f ? v : s * v;
                    if (outf) {
                        outf[(size_t)r * C + n] = v;
                    } else {
                        ushort hh, ll;
                        split_bf16(v, hh, ll);
                        outh[(size_t)r * C + n] = hh;
                        outl[(size_t)r * C + n] = ll;
                    }
                }
            }
        }
    }
}

// ---------------- launch ----------------

extern "C" void kernel_launch(void* const* d_in, const int* in_sizes, int n_in,
                              void* d_out, int out_size, void* d_ws, size_t ws_size,
                              hipStream_t stream) {
    const float* x   = (const float*)d_in[0];
    const int*   src = (const int*)d_in[1];
    const int*   dst = src + NE;
    const float* Wl[3] = {(const float*)d_in[3], (const float*)d_in[7],  (const float*)d_in[11]};
    const float* bl[3] = {(const float*)d_in[4], (const float*)d_in[8],  (const float*)d_in[12]};
    const float* Wr[3] = {(const float*)d_in[5], (const float*)d_in[9],  (const float*)d_in[13]};
    const float* sl[3] = {(const float*)d_in[6], (const float*)d_in[10], (const float*)d_in[14]};

    int*   deg     = (int*)d_ws;             // 50016
    int*   row_ptr = deg + 50016;            // 50016 (uses 50001)
    int*   col     = row_ptr + 50016;        // 800000
    int*   pos     = col + 800000;           // 800000
    int*   bsum    = pos + 800000;           // 256
    int*   boff    = bsum + 256;             // 256
    ushort* Gh     = (ushort*)(boff + 256);  // agg hi, NN*C
    ushort* Gl     = Gh + (size_t)NN * C;    // agg lo
    ushort* Ah     = Gl + (size_t)NN * C;    // ping hi
    ushort* Al     = Ah + (size_t)NN * C;    // ping lo
    ushort* Bh     = Al + (size_t)NN * C;    // pong hi
    ushort* Bl     = Bh + (size_t)NN * C;    // pong lo

    hipMemsetAsync(deg, 0, 50016 * sizeof(int), stream);

    count_split_kernel<<<E8B + SPLITB, 256, 0, stream>>>(dst, x, deg, pos, Ah, Al);
    scan1_kernel<<<SCAN_BLOCKS, 256, 0, stream>>>(deg, row_ptr, bsum);
    scan2_kernel<<<1, 256, 0, stream>>>(bsum, boff);
    fill2_kernel<<<E8B, 256, 0, stream>>>(src, dst, row_ptr, boff, pos, col);

    int rows_out = out_size / C;             // 1024

    // layer 0: A -> B
    agg_kernel<<<(NN + 3) / 4, 256, 0, stream>>>(Ah, row_ptr, boff, col, Gh, Gl, NN);
    gemm_kernel<<<(NN + 63) / 64, 256, 0, stream>>>(Gh, Gl, Ah, Al, Wl[0], bl[0], Wr[0], sl[0],
                                                    nullptr, Bh, Bl, NN);

    // layer 1: B -> A
    agg_kernel<<<(NN + 3) / 4, 256, 0, stream>>>(Bh, row_ptr, boff, col, Gh, Gl, NN);
    gemm_kernel<<<(NN + 63) / 64, 256, 0, stream>>>(Gh, Gl, Bh, Bl, Wl[1], bl[1], Wr[1], sl[1],
                                                    nullptr, Ah, Al, NN);

    // layer 2: A -> d_out (first rows_out nodes only)
    agg_kernel<<<(rows_out + 3) / 4, 256, 0, stream>>>(Ah, row_ptr, boff, col, Gh, Gl, rows_out);
    gemm_kernel<<<(rows_out + 63) / 64, 256, 0, stream>>>(Gh, Gl, Ah, Al, Wl[2], bl[2], Wr[2], sl[2],
                                                          (float*)d_out, nullptr, nullptr, rows_out);
}

// Round 11
// 301.793 us; speedup vs baseline: 1.7774x; 1.0345x over previous
//
#include <hip/hip_runtime.h>

#define NN 50000
#define NE 800000
#define C 128
#define SCAN_BLOCKS ((NN + 255) / 256)   // 196
#define EB2 ((NE / 2 + 255) / 256)       // 1563 edge blocks (2 edges/thread)
#define SPLITB 1563                      // x-split blocks
#define WB 96                            // W-split blocks: 6*16384 floats / 4 / 256
#define EB4 ((NE / 4 + 255) / 256)       // 782 fill blocks (4 edges/thread)
#define ASTRIDE 136                      // bf16 elems per LDS A row (16B-aligned rows, 2-way max)

typedef __attribute__((ext_vector_type(8))) short bf16x8;
typedef __attribute__((ext_vector_type(4))) float f32x4;
typedef unsigned short ushort;

__device__ inline ushort bf16_rn(float f) {
    unsigned u = __builtin_bit_cast(unsigned, f);
    u += 0x7FFF + ((u >> 16) & 1);
    return (ushort)(u >> 16);
}
__device__ inline void split_bf16(float f, ushort& hi, ushort& lo) {
    hi = bf16_rn(f);
    float hif = __builtin_bit_cast(float, (unsigned)hi << 16);
    lo = bf16_rn(f - hif);               // residual, ~2^-17 rel total
}
__device__ inline float bf_lo(unsigned u) { return __builtin_bit_cast(float, u << 16); }
__device__ inline float bf_hi(unsigned u) { return __builtin_bit_cast(float, u & 0xFFFF0000u); }

// ---- fused prep: count_pos (edges) + split x + split W, partitioned by block range ----

__global__ __launch_bounds__(256)
void prep_kernel(const int* __restrict__ dst, const float* __restrict__ x,
                 const float* __restrict__ W0, const float* __restrict__ W1,
                 const float* __restrict__ W2, const float* __restrict__ W3,
                 const float* __restrict__ W4, const float* __restrict__ W5,
                 int* __restrict__ deg, int* __restrict__ pos,
                 ushort* __restrict__ Ah, ushort* __restrict__ Al,
                 ushort* __restrict__ Wh, ushort* __restrict__ Wl) {
    int t = threadIdx.x;
    if (blockIdx.x < EB2) {
        // edge phase: 2 edges/thread, 400k threads -> atomic latency well hidden
        int e0 = (blockIdx.x * 256 + t) * 2;
        if (e0 < NE) {
            int2 d2 = *(const int2*)(dst + e0);
            int p0 = atomicAdd(&deg[d2.x], 1);
            int p1 = atomicAdd(&deg[d2.y], 1);
            *(int2*)(pos + e0) = make_int2(p0, p1);
        }
    } else if (blockIdx.x < EB2 + SPLITB) {
        // x split phase (grid-stride over 1.6M f32x4)
        int tid = (blockIdx.x - EB2) * 256 + t;
        const int total = NN * C / 4;
        for (int i = tid; i < total; i += SPLITB * 256) {
            f32x4 v = ((const f32x4*)x)[i];
            ushort h0, h1, h2, h3, l0, l1, l2, l3;
            split_bf16(v.x, h0, l0);
            split_bf16(v.y, h1, l1);
            split_bf16(v.z, h2, l2);
            split_bf16(v.w, h3, l3);
            *(uint2*)(Ah + (size_t)i * 4) = make_uint2((unsigned)h0 | ((unsigned)h1 << 16),
                                                       (unsigned)h2 | ((unsigned)h3 << 16));
            *(uint2*)(Al + (size_t)i * 4) = make_uint2((unsigned)l0 | ((unsigned)l1 << 16),
                                                       (unsigned)l2 | ((unsigned)l3 << 16));
        }
    } else {
        // W split phase: 6 matrices x 16384 floats = 24576 f32x4, exactly WB*256 threads
        const float* Ws[6] = {W0, W1, W2, W3, W4, W5};
        int i = (blockIdx.x - EB2 - SPLITB) * 256 + t;     // f32x4 index
        int mat = i >> 12;                                  // 4096 f32x4 per matrix
        f32x4 v = ((const f32x4*)Ws[mat])[i & 4095];
        ushort h0, h1, h2, h3, l0, l1, l2, l3;
        split_bf16(v.x, h0, l0);
        split_bf16(v.y, h1, l1);
        split_bf16(v.z, h2, l2);
        split_bf16(v.w, h3, l3);
        *(uint2*)(Wh + (size_t)i * 4) = make_uint2((unsigned)h0 | ((unsigned)h1 << 16),
                                                   (unsigned)h2 | ((unsigned)h3 << 16));
        *(uint2*)(Wl + (size_t)i * 4) = make_uint2((unsigned)l0 | ((unsigned)l1 << 16),
                                                   (unsigned)l2 | ((unsigned)l3 << 16));
    }
}

// ---- scan1: block-local exclusive scan of deg (row_ptr stays block-local) ----

__global__ __launch_bounds__(256)
void scan1_kernel(const int* __restrict__ deg, int* __restrict__ row_ptr,
                  int* __restrict__ bsum) {
    __shared__ int wsum[4];
    __shared__ int wpre[4];
    int t = threadIdx.x, lane = t & 63, w = t >> 6;
    int i = blockIdx.x * 256 + t;
    int v = (i < NN) ? deg[i] : 0;
    int s = v;
    #pragma unroll
    for (int off = 1; off < 64; off <<= 1) {
        int y = __shfl_up(s, off, 64);
        if (lane >= off) s += y;
    }
    if (lane == 63) wsum[w] = s;
    __syncthreads();
    if (t == 0) {
        int acc = 0;
        #pragma unroll
        for (int j = 0; j < 4; ++j) { wpre[j] = acc; acc += wsum[j]; }
        bsum[blockIdx.x] = acc;
    }
    __syncthreads();
    if (i <= NN) row_ptr[i] = wpre[w] + (s - v);   // block-local exclusive
}

// ---- scan2: block offsets (exclusive scan of the 196 block sums) ----

__global__ __launch_bounds__(256)
void scan2_kernel(const int* __restrict__ bsum, int* __restrict__ boff) {
    __shared__ int wsum[4];
    __shared__ int wpre[4];
    int t = threadIdx.x, lane = t & 63, w = t >> 6;
    int v = (t < SCAN_BLOCKS) ? bsum[t] : 0;
    int s = v;
    #pragma unroll
    for (int off = 1; off < 64; off <<= 1) {
        int y = __shfl_up(s, off, 64);
        if (lane >= off) s += y;
    }
    if (lane == 63) wsum[w] = s;
    __syncthreads();
    if (t == 0) {
        int acc = 0;
        #pragma unroll
        for (int j = 0; j < 4; ++j) { wpre[j] = acc; acc += wsum[j]; }
    }
    __syncthreads();
    if (t < SCAN_BLOCKS) boff[t] = wpre[w] + (s - v);
}

// ---- fill: placement, atomic-free; global base = rp[d] + boff[d>>8]; 4 edges/thread ----

__global__ __launch_bounds__(256)
void fill2_kernel(const int* __restrict__ src, const int* __restrict__ dst,
                  const int* __restrict__ row_ptr, const int* __restrict__ boff,
                  const int* __restrict__ pos, int* __restrict__ col) {
    int e0 = (blockIdx.x * 256 + threadIdx.x) * 4;
    if (e0 >= NE) return;
    int4 da = *(const int4*)(dst + e0);
    int4 sa = *(const int4*)(src + e0);
    int4 pa = *(const int4*)(pos + e0);
    col[row_ptr[da.x] + boff[da.x >> 8] + pa.x] = sa.x;
    col[row_ptr[da.y] + boff[da.y >> 8] + pa.y] = sa.y;
    col[row_ptr[da.z] + boff[da.z >> 8] + pa.z] = sa.z;
    col[row_ptr[da.w] + boff[da.w >> 8] + pa.w] = sa.w;
}

// ---- mean aggregation: one wave per node, 4 edge-rows per VMEM instr ----
// Row = 256 B of bf16-hi. 16 lanes x uint4 per edge-row; quad picks 1 of 4 edges.
// Epilogue: mean -> split hi/lo -> 16B stores (feeds gemm A-operand directly).

__global__ __launch_bounds__(256)
void agg_kernel(const ushort* __restrict__ xh, const int* __restrict__ row_ptr,
                const int* __restrict__ boff, const int* __restrict__ col,
                ushort* __restrict__ aggh, ushort* __restrict__ aggl, int nodes) {
    int node = (blockIdx.x * blockDim.x + threadIdx.x) >> 6;
    int lane = threadIdx.x & 63;
    if (node >= nodes) return;
    int quad = lane >> 4;        // which edge within a group of 4
    int ql   = lane & 15;        // channel group: ch [ql*8, ql*8+8)
    int start = row_ptr[node] + boff[node >> 8];
    int end   = row_ptr[node + 1] + boff[(node + 1) >> 8];
    const uint4* xr = (const uint4*)xh;   // row = 16 uint4
    float a0=0,a1=0,a2=0,a3=0,a4=0,a5=0,a6=0,a7=0;
    int e = start;
    for (; e + 7 < end; e += 8) {
        int i0 = col[e + quad];
        int i1 = col[e + 4 + quad];
        uint4 u0 = xr[(size_t)i0 * 16 + ql];
        uint4 u1 = xr[(size_t)i1 * 16 + ql];
        a0 += bf_lo(u0.x) + bf_lo(u1.x); a1 += bf_hi(u0.x) + bf_hi(u1.x);
        a2 += bf_lo(u0.y) + bf_lo(u1.y); a3 += bf_hi(u0.y) + bf_hi(u1.y);
        a4 += bf_lo(u0.z) + bf_lo(u1.z); a5 += bf_hi(u0.z) + bf_hi(u1.z);
        a6 += bf_lo(u0.w) + bf_lo(u1.w); a7 += bf_hi(u0.w) + bf_hi(u1.w);
    }
    for (; e + 3 < end; e += 4) {
        uint4 u = xr[(size_t)col[e + quad] * 16 + ql];
        a0 += bf_lo(u.x); a1 += bf_hi(u.x);
        a2 += bf_lo(u.y); a3 += bf_hi(u.y);
        a4 += bf_lo(u.z); a5 += bf_hi(u.z);
        a6 += bf_lo(u.w); a7 += bf_hi(u.w);
    }
    int rem = end - e;           // 0..3
    if (quad < rem) {
        uint4 u = xr[(size_t)col[e + quad] * 16 + ql];
        a0 += bf_lo(u.x); a1 += bf_hi(u.x);
        a2 += bf_lo(u.y); a3 += bf_hi(u.y);
        a4 += bf_lo(u.z); a5 += bf_hi(u.z);
        a6 += bf_lo(u.w); a7 += bf_hi(u.w);
    }
    // reduce across the 4 quads (lanes ql, ql+16, ql+32, ql+48)
    a0 += __shfl_xor(a0, 16, 64); a0 += __shfl_xor(a0, 32, 64);
    a1 += __shfl_xor(a1, 16, 64); a1 += __shfl_xor(a1, 32, 64);
    a2 += __shfl_xor(a2, 16, 64); a2 += __shfl_xor(a2, 32, 64);
    a3 += __shfl_xor(a3, 16, 64); a3 += __shfl_xor(a3, 32, 64);
    a4 += __shfl_xor(a4, 16, 64); a4 += __shfl_xor(a4, 32, 64);
    a5 += __shfl_xor(a5, 16, 64); a5 += __shfl_xor(a5, 32, 64);
    a6 += __shfl_xor(a6, 16, 64); a6 += __shfl_xor(a6, 32, 64);
    a7 += __shfl_xor(a7, 16, 64); a7 += __shfl_xor(a7, 32, 64);
    if (quad == 0) {
        float inv = 1.0f / (float)max(end - start, 1);
        float m[8] = {a0*inv, a1*inv, a2*inv, a3*inv, a4*inv, a5*inv, a6*inv, a7*inv};
        ushort h[8], o[8];
        #pragma unroll
        for (int j = 0; j < 8; ++j) split_bf16(m[j], h[j], o[j]);
        size_t off = (size_t)node * C + ql * 8;
        *(uint4*)(aggh + off) = make_uint4((unsigned)h[0] | ((unsigned)h[1] << 16),
                                           (unsigned)h[2] | ((unsigned)h[3] << 16),
                                           (unsigned)h[4] | ((unsigned)h[5] << 16),
                                           (unsigned)h[6] | ((unsigned)h[7] << 16));
        *(uint4*)(aggl + off) = make_uint4((unsigned)o[0] | ((unsigned)o[1] << 16),
                                           (unsigned)o[2] | ((unsigned)o[3] << 16),
                                           (unsigned)o[4] | ((unsigned)o[5] << 16),
                                           (unsigned)o[6] | ((unsigned)o[7] << 16));
    }
}

// ---- fused dual GEMM + bias + PReLU via split-bf16 MFMA ----
// out = prelu( A@Wl.T + bl + X@Wr.T ); operands AND weights pre-split hi/lo.
// block = 256 (4 waves), tile 64 rows x 128 cols; wave = 32-col strip.

__global__ __launch_bounds__(256, 3)
void gemm_kernel(const ushort* __restrict__ Ah, const ushort* __restrict__ Al,
                 const ushort* __restrict__ Xh, const ushort* __restrict__ Xl,
                 const ushort* __restrict__ Wlh, const ushort* __restrict__ Wll,
                 const ushort* __restrict__ Wrh, const ushort* __restrict__ Wrl,
                 const float* __restrict__ bl, const float* __restrict__ slope,
                 float* __restrict__ outf, ushort* __restrict__ outh,
                 ushort* __restrict__ outl, int rows) {
    __shared__ ushort Ahi[64 * ASTRIDE];
    __shared__ ushort Alo[64 * ASTRIDE];
    int t = threadIdx.x;
    int lane = t & 63;
    int w = t >> 6;
    int l = lane & 15;
    int q = lane >> 4;
    int row0 = blockIdx.x * 64;

    f32x4 acc[4][2];
    #pragma unroll
    for (int mt = 0; mt < 4; ++mt)
        #pragma unroll
        for (int nt = 0; nt < 2; ++nt)
            acc[mt][nt] = (f32x4){0.f, 0.f, 0.f, 0.f};

    #pragma unroll
    for (int mat = 0; mat < 2; ++mat) {
        const ushort* WH = mat ? Wrh : Wlh;
        const ushort* WL = mat ? Wrl : Wll;
        const ushort* Ph = mat ? Xh : Ah;
        const ushort* Pl = mat ? Xl : Al;

        // W fragments direct from pre-split arrays: B[k][n], n = lane&15, k = q*8+j
        bf16x8 bhi[2][4], blo[2][4];
        #pragma unroll
        for (int nt = 0; nt < 2; ++nt) {
            int n = w * 32 + nt * 16 + l;
            const ushort* wp = WH + (size_t)n * C + q * 8;
            const ushort* wq = WL + (size_t)n * C + q * 8;
            #pragma unroll
            for (int kb = 0; kb < 4; ++kb) {
                bhi[nt][kb] = *(const bf16x8*)(wp + kb * 32);
                blo[nt][kb] = *(const bf16x8*)(wq + kb * 32);
            }
        }

        __syncthreads();                 // protect previous mat's frag reads
        int ar = t >> 2;                 // row 0..63
        int aq = t & 3;                  // k quarter: 32 ushorts
        int r = min(row0 + ar, rows - 1);
        ushort* dh = Ahi + ar * ASTRIDE + aq * 32;
        ushort* dl = Alo + ar * ASTRIDE + aq * 32;
        const ushort* ph = Ph + (size_t)r * C + aq * 32;
        const ushort* pl = Pl + (size_t)r * C + aq * 32;
        #pragma unroll
        for (int i = 0; i < 4; ++i) {    // 4 x uint4 = 32 ushorts
            *(uint4*)(dh + i * 8) = *(const uint4*)(ph + i * 8);
            *(uint4*)(dl + i * 8) = *(const uint4*)(pl + i * 8);
        }
        __syncthreads();

        // K loop: 4 k-blocks x 4 m-tiles x 2 n-tiles x 3 products
        #pragma unroll
        for (int kb = 0; kb < 4; ++kb) {
            #pragma unroll
            for (int mt = 0; mt < 4; ++mt) {
                int off = (mt * 16 + l) * ASTRIDE + kb * 32 + q * 8;
                bf16x8 ahi = *(const bf16x8*)(Ahi + off);
                bf16x8 alo = *(const bf16x8*)(Alo + off);
                #pragma unroll
                for (int nt = 0; nt < 2; ++nt) {
                    acc[mt][nt] = __builtin_amdgcn_mfma_f32_16x16x32_bf16(ahi, bhi[nt][kb], acc[mt][nt], 0, 0, 0);
                    acc[mt][nt] = __builtin_amdgcn_mfma_f32_16x16x32_bf16(alo, bhi[nt][kb], acc[mt][nt], 0, 0, 0);
                    acc[mt][nt] = __builtin_amdgcn_mfma_f32_16x16x32_bf16(ahi, blo[nt][kb], acc[mt][nt], 0, 0, 0);
                }
            }
        }
    }

    // epilogue: bias + PReLU; write fp32 (final layer) or hi/lo (hidden layers)
    #pragma unroll
    for (int nt = 0; nt < 2; ++nt) {
        int n = w * 32 + nt * 16 + l;
        float b = bl[n], s = slope[n];
        #pragma unroll
        for (int mt = 0; mt < 4; ++mt) {
            #pragma unroll
            for (int rg = 0; rg < 4; ++rg) {
                int r = row0 + mt * 16 + q * 4 + rg;
                if (r < rows) {
                    float v = acc[mt][nt][rg] + b;
                    v = v > 0.f ? v : s * v;
                    if (outf) {
                        outf[(size_t)r * C + n] = v;
                    } else {
                        ushort hh, ll;
                        split_bf16(v, hh, ll);
                        outh[(size_t)r * C + n] = hh;
                        outl[(size_t)r * C + n] = ll;
                    }
                }
            }
        }
    }
}

// ---------------- launch ----------------

extern "C" void kernel_launch(void* const* d_in, const int* in_sizes, int n_in,
                              void* d_out, int out_size, void* d_ws, size_t ws_size,
                              hipStream_t stream) {
    const float* x   = (const float*)d_in[0];
    const int*   src = (const int*)d_in[1];
    const int*   dst = src + NE;
    const float* Wl[3] = {(const float*)d_in[3], (const float*)d_in[7],  (const float*)d_in[11]};
    const float* bl[3] = {(const float*)d_in[4], (const float*)d_in[8],  (const float*)d_in[12]};
    const float* Wr[3] = {(const float*)d_in[5], (const float*)d_in[9],  (const float*)d_in[13]};
    const float* sl[3] = {(const float*)d_in[6], (const float*)d_in[10], (const float*)d_in[14]};

    int*   deg     = (int*)d_ws;             // 50016
    int*   row_ptr = deg + 50016;            // 50016 (uses 50001)
    int*   col     = row_ptr + 50016;        // 800000
    int*   pos     = col + 800000;           // 800000
    int*   bsum    = pos + 800000;           // 256
    int*   boff    = bsum + 256;             // 256
    ushort* Whs    = (ushort*)(boff + 256);  // 6*16384 pre-split W hi
    ushort* Wls    = Whs + 6 * 16384;        // 6*16384 pre-split W lo
    ushort* Gh     = Wls + 6 * 16384;        // agg hi, NN*C
    ushort* Gl     = Gh + (size_t)NN * C;    // agg lo
    ushort* Ah     = Gl + (size_t)NN * C;    // ping hi
    ushort* Al     = Ah + (size_t)NN * C;    // ping lo
    ushort* Bh     = Al + (size_t)NN * C;    // pong hi
    ushort* Bl     = Bh + (size_t)NN * C;    // pong lo

    hipMemsetAsync(deg, 0, 50016 * sizeof(int), stream);

    // W order: Wl0, Wr0, Wl1, Wr1, Wl2, Wr2
    prep_kernel<<<EB2 + SPLITB + WB, 256, 0, stream>>>(
        dst, x, Wl[0], Wr[0], Wl[1], Wr[1], Wl[2], Wr[2],
        deg, pos, Ah, Al, Whs, Wls);
    scan1_kernel<<<SCAN_BLOCKS, 256, 0, stream>>>(deg, row_ptr, bsum);
    scan2_kernel<<<1, 256, 0, stream>>>(bsum, boff);
    fill2_kernel<<<EB4, 256, 0, stream>>>(src, dst, row_ptr, boff, pos, col);

    int rows_out = out_size / C;             // 1024

    // layer 0: A -> B
    agg_kernel<<<(NN + 3) / 4, 256, 0, stream>>>(Ah, row_ptr, boff, col, Gh, Gl, NN);
    gemm_kernel<<<(NN + 63) / 64, 256, 0, stream>>>(Gh, Gl, Ah, Al,
                                                    Whs + 0 * 16384, Wls + 0 * 16384,
                                                    Whs + 1 * 16384, Wls + 1 * 16384,
                                                    bl[0], sl[0], nullptr, Bh, Bl, NN);

    // layer 1: B -> A
    agg_kernel<<<(NN + 3) / 4, 256, 0, stream>>>(Bh, row_ptr, boff, col, Gh, Gl, NN);
    gemm_kernel<<<(NN + 63) / 64, 256, 0, stream>>>(Gh, Gl, Bh, Bl,
                                                    Whs + 2 * 16384, Wls + 2 * 16384,
                                                    Whs + 3 * 16384, Wls + 3 * 16384,
                                                    bl[1], sl[1], nullptr, Ah, Al, NN);

    // layer 2: A -> d_out (first rows_out nodes only)
    agg_kernel<<<(rows_out + 3) / 4, 256, 0, stream>>>(Ah, row_ptr, boff, col, Gh, Gl, rows_out);
    gemm_kernel<<<(rows_out + 63) / 64, 256, 0, stream>>>(Gh, Gl, Ah, Al,
                                                          Whs + 4 * 16384, Wls + 4 * 16384,
                                                          Whs + 5 * 16384, Wls + 5 * 16384,
                                                          bl[2], sl[2], (float*)d_out, nullptr, nullptr,
                                                          rows_out);
}